// Round 11
// baseline (130.964 us; speedup 1.0000x reference)
//
#include <hip/hip_runtime.h>
#include <hip/hip_bf16.h>

#define D 128
#define FEPS 1e-15f
#define PROJ_EPS 1e-5f

typedef __attribute__((ext_vector_type(8))) short short8v;
typedef __attribute__((ext_vector_type(4))) float f32x4;

__device__ __forceinline__ unsigned pack_bf16x2(float lo, float hi) {
    __hip_bfloat16 h0 = __float2bfloat16(lo);
    __hip_bfloat16 h1 = __float2bfloat16(hi);
    unsigned u0 = *reinterpret_cast<unsigned short*>(&h0);
    unsigned u1 = *reinterpret_cast<unsigned short*>(&h1);
    return u0 | (u1 << 16);
}

__device__ __forceinline__ float bf_lo(unsigned u) { return __uint_as_float(u << 16); }
__device__ __forceinline__ float bf_hi(unsigned u) { return __uint_as_float(u & 0xffff0000u); }

__device__ __forceinline__ float fast_tanh_clamped(float n) {
    float nc = fminf(n, 15.f);
    float e2 = __expf(2.f * nc);
    return 1.f - __fdividef(2.f, e2 + 1.f);
}

// ---- edge histogram (standalone; runs before scans) ----
__global__ __launch_bounds__(512) void k_hist(const int* __restrict__ rowi,
                                              int* __restrict__ cnt, int E) {
    int e = blockIdx.x * 512 + threadIdx.x;
    if (e < E) atomicAdd(&cnt[rowi[e]], 1);
}

// ---- CSR scan chain (multi-block, proven) ----
__global__ __launch_bounds__(256) void k_scan1(const int* __restrict__ cnt,
                                               int* __restrict__ ex,
                                               int* __restrict__ bsum, int Nn) {
    __shared__ int ts[256];
    int t = threadIdx.x, b = blockIdx.x;
    int base = b * 1024 + t * 4;
    int v0 = (base + 0 < Nn) ? cnt[base + 0] : 0;
    int v1 = (base + 1 < Nn) ? cnt[base + 1] : 0;
    int v2 = (base + 2 < Nn) ? cnt[base + 2] : 0;
    int v3 = (base + 3 < Nn) ? cnt[base + 3] : 0;
    int s = v0 + v1 + v2 + v3;
    ts[t] = s;
    __syncthreads();
    for (int off = 1; off < 256; off <<= 1) {
        int add = (t >= off) ? ts[t - off] : 0;
        __syncthreads();
        ts[t] += add;
        __syncthreads();
    }
    int excl = ts[t] - s;
    if (t == 255) bsum[b] = ts[t];
    if (base + 0 < Nn) ex[base + 0] = excl;
    if (base + 1 < Nn) ex[base + 1] = excl + v0;
    if (base + 2 < Nn) ex[base + 2] = excl + v0 + v1;
    if (base + 3 < Nn) ex[base + 3] = excl + v0 + v1 + v2;
}

__global__ void k_scan2(const int* __restrict__ bsum, int* __restrict__ bsumx, int nb) {
    __shared__ int ts[128];
    int t = threadIdx.x;
    int v = (t < nb) ? bsum[t] : 0;
    ts[t] = v;
    __syncthreads();
    for (int off = 1; off < 128; off <<= 1) {
        int add = (t >= off) ? ts[t - off] : 0;
        __syncthreads();
        ts[t] += add;
        __syncthreads();
    }
    bsumx[t] = ts[t] - v;   // exclusive
}

__global__ __launch_bounds__(256) void k_scan3(int* __restrict__ rowptr,
                                               const int* __restrict__ bsumx,
                                               int* __restrict__ cursor, int Nn, int E) {
    int i = blockIdx.x * 256 + threadIdx.x;
    if (i < Nn) {
        int v = rowptr[i] + bsumx[i >> 10];
        rowptr[i] = v;
        cursor[i] = v;
    }
    if (i == 0) rowptr[Nn] = E;
}

// ---- fused persistent MFMA GEMM (mapped = logmap(x) @ W) + CSR scatter ----
// blocks [0,GBg): persistent gemm — W staged ONCE, zero-barrier tile loop,
//                 wave-private C staging in separate LDS region.
// blocks [GBg,GBg+SBs): grid-stride CSR scatter w/ nontemporal 8B stores.
__global__ __launch_bounds__(512) void k_gemm_scatter(
    const float* __restrict__ x, const float* __restrict__ W,
    __hip_bfloat16* __restrict__ mapped, int Nn, int NT, int GBg, int SBs,
    const int* __restrict__ rowi, const int* __restrict__ coli,
    const float* __restrict__ val, int* __restrict__ cursor,
    long long* __restrict__ sedge, int E)
{
    __shared__ uint4 lsW4[2048];   // 32 KB: W^T, staged once, read-only after
    __shared__ uint4 lsC4[2048];   // 32 KB: C staging, wave-private 4 KB slices

    const int tid = threadIdx.x;

    if (blockIdx.x >= GBg) {
        // ---- scatter role: NT store kills write-allocate line waste ----
        const int stride = SBs * 512;
        int e = (blockIdx.x - GBg) * 512 + tid;
#pragma unroll 2
        for (; e < E; e += stride) {
            int cv = coli[e];
            float vv = val[e];
            int p = atomicAdd(&cursor[rowi[e]], 1);
            long long pkt = ((long long)(unsigned)__float_as_int(vv) << 32) | (unsigned)cv;
            __builtin_nontemporal_store(pkt, &sedge[p]);
        }
        return;
    }

    const int w = tid >> 6, l = tid & 63;
    const int q = l & 15, khi = l >> 4;

    // ---- stage W^T once, bank-balanced XOR layout ----
#pragma unroll
    for (int it = 0; it < 4; ++it) {
        int i = it * 512 + tid;
        int col = i & 127, kg = i >> 7;
        unsigned p0 = pack_bf16x2(W[(kg * 8 + 0) * D + col], W[(kg * 8 + 1) * D + col]);
        unsigned p1 = pack_bf16x2(W[(kg * 8 + 2) * D + col], W[(kg * 8 + 3) * D + col]);
        unsigned p2 = pack_bf16x2(W[(kg * 8 + 4) * D + col], W[(kg * 8 + 5) * D + col]);
        unsigned p3 = pack_bf16x2(W[(kg * 8 + 6) * D + col], W[(kg * 8 + 7) * D + col]);
        lsW4[col * 16 + (kg ^ (col & 15))] = make_uint4(p0, p1, p2, p3);
    }
    __syncthreads();   // the ONLY barrier — tile loop below is barrier-free

    const short8v* lsB = (const short8v*)lsW4;
    unsigned* lsc = (unsigned*)lsC4;
    const int cbase = w * 1024;            // wave-private 4 KB (1024 words)

#pragma unroll 1
    for (int tt = blockIdx.x; tt < NT; tt += GBg) {
        const int rowbase = tt * 128;
        const int row = rowbase + w * 16 + q;
        const bool rv = row < Nn;
        const float* xr = x + (size_t)row * D;
        float4 xa[8];
        float nn = 0.f;
#pragma unroll
        for (int ks = 0; ks < 4; ++ks) {
            float4 p0 = make_float4(0.f, 0.f, 0.f, 0.f), p1 = p0;
            if (rv) {
                p0 = *reinterpret_cast<const float4*>(xr + ks * 32 + khi * 8);
                p1 = *reinterpret_cast<const float4*>(xr + ks * 32 + khi * 8 + 4);
            }
            xa[2 * ks] = p0; xa[2 * ks + 1] = p1;
            nn += p0.x * p0.x + p0.y * p0.y + p0.z * p0.z + p0.w * p0.w
                + p1.x * p1.x + p1.y * p1.y + p1.z * p1.z + p1.w * p1.w;
        }
        nn += __shfl_xor(nn, 16, 64);
        nn += __shfl_xor(nn, 32, 64);       // full 128-dim row norm^2
        float n = fmaxf(sqrtf(nn), FEPS);
        float c = fminf(n, 1.f - 1e-7f);
        float s = __fdividef(0.5f * __logf(__fdividef(1.f + c, 1.f - c)), n);

        union { unsigned u[4]; short8v v; } af[4];
#pragma unroll
        for (int ks = 0; ks < 4; ++ks) {
            float4 p0 = xa[2 * ks], p1 = xa[2 * ks + 1];
            af[ks].u[0] = pack_bf16x2(s * p0.x, s * p0.y);
            af[ks].u[1] = pack_bf16x2(s * p0.z, s * p0.w);
            af[ks].u[2] = pack_bf16x2(s * p1.x, s * p1.y);
            af[ks].u[3] = pack_bf16x2(s * p1.z, s * p1.w);
        }

        f32x4 acc[8];
#pragma unroll
        for (int t = 0; t < 8; ++t) acc[t] = (f32x4){0.f, 0.f, 0.f, 0.f};

#pragma unroll
        for (int ks = 0; ks < 4; ++ks) {
#pragma unroll
            for (int t = 0; t < 8; ++t) {
                short8v b = lsB[(t * 16 + q) * 16 + ((ks * 4 + khi) ^ q)];
                acc[t] = __builtin_amdgcn_mfma_f32_16x16x32_bf16(af[ks].v, b, acc[t], 0, 0, 0);
            }
        }

        // ---- C staging: wave-private LDS slice, no barriers ----
#pragma unroll
        for (int t = 0; t < 8; ++t) {
#pragma unroll
            for (int r = 0; r < 4; ++r) {
                float self = acc[t][r];
                float other = __shfl_xor(self, 1, 64);
                unsigned pw = (q & 1) ? pack_bf16x2(other, self) : pack_bf16x2(self, other);
                int rl = khi * 4 + r;               // local row 0..15
                int cp = t * 8 + (q >> 1);
                lsc[cbase + rl * 64 + (cp ^ (khi << 3))] = pw;
            }
        }
        // readback own rows, coalesced 16-B/lane global stores
#pragma unroll
        for (int i4 = 0; i4 < 4; ++i4) {
            int rl = i4 * 4 + (l >> 4);             // local row 0..15
            int ro = rowbase + w * 16 + rl;
            int cp4 = (l & 15) * 4;
            uint4 vv = lsC4[(cbase + rl * 64 + (cp4 ^ (i4 << 3))) >> 2];
            if (ro < Nn)
                *reinterpret_cast<uint4*>(mapped + (size_t)ro * D + (l & 15) * 8) = vv;
        }
    }
}

// ---- fused: bias + CSR gather-reduce + expmap + proj + mobius + proj ----
// 16-lane groups: 4 rows/wave, lane l owns dims (l&15)*8..+8 (R8-proven, 44 us)
__global__ __launch_bounds__(256) void k_aggfin(
    const uint4* __restrict__ mapped4, const int2* __restrict__ sedge,
    const int* __restrict__ rowptr, const float* __restrict__ bias,
    float* __restrict__ out, int Nn)
{
    const int tid = threadIdx.x;
    const int w = tid >> 6, l = tid & 63;
    const int g = l >> 4, q = l & 15;
    const int row = blockIdx.x * 16 + w * 4 + g;

    // bias point (identical computation in each 16-lane group)
    float4 rb0 = *reinterpret_cast<const float4*>(bias + q * 8);
    float4 rb1 = *reinterpret_cast<const float4*>(bias + q * 8 + 4);
    float bn2 = rb0.x * rb0.x + rb0.y * rb0.y + rb0.z * rb0.z + rb0.w * rb0.w
              + rb1.x * rb1.x + rb1.y * rb1.y + rb1.z * rb1.z + rb1.w * rb1.w;
#pragma unroll
    for (int o = 8; o > 0; o >>= 1) bn2 += __shfl_xor(bn2, o, 64);
    float bn = fmaxf(sqrtf(bn2), FEPS);
    float bt = fast_tanh_clamped(bn);
    float bs = __fdividef(bt, bn);
    float ben2 = bs * bs * bn2;
    float bpn = fmaxf(sqrtf(ben2), FEPS);
    float bps = fminf(1.f, __fdividef(1.f - PROJ_EPS, bpn));
    float bsc = bs * bps;
    float y2 = bps * bps * ben2;
    float bj[8] = { rb0.x * bsc, rb0.y * bsc, rb0.z * bsc, rb0.w * bsc,
                    rb1.x * bsc, rb1.y * bsc, rb1.z * bsc, rb1.w * bsc };

    if (row >= Nn) return;
    int beg = rowptr[row], end = rowptr[row + 1];

    float acc[8] = {0.f, 0.f, 0.f, 0.f, 0.f, 0.f, 0.f, 0.f};
    int e = beg;
    for (; e + 3 < end; e += 4) {         // 4 gathers in flight
        int2 d0 = sedge[e], d1 = sedge[e + 1], d2 = sedge[e + 2], d3 = sedge[e + 3];
        uint4 u0 = mapped4[(size_t)d0.x * 16 + q];
        uint4 u1 = mapped4[(size_t)d1.x * 16 + q];
        uint4 u2 = mapped4[(size_t)d2.x * 16 + q];
        uint4 u3 = mapped4[(size_t)d3.x * 16 + q];
        float v0 = __int_as_float(d0.y), v1 = __int_as_float(d1.y);
        float v2 = __int_as_float(d2.y), v3 = __int_as_float(d3.y);
        acc[0] += v0 * bf_lo(u0.x); acc[1] += v0 * bf_hi(u0.x);
        acc[2] += v0 * bf_lo(u0.y); acc[3] += v0 * bf_hi(u0.y);
        acc[4] += v0 * bf_lo(u0.z); acc[5] += v0 * bf_hi(u0.z);
        acc[6] += v0 * bf_lo(u0.w); acc[7] += v0 * bf_hi(u0.w);
        acc[0] += v1 * bf_lo(u1.x); acc[1] += v1 * bf_hi(u1.x);
        acc[2] += v1 * bf_lo(u1.y); acc[3] += v1 * bf_hi(u1.y);
        acc[4] += v1 * bf_lo(u1.z); acc[5] += v1 * bf_hi(u1.z);
        acc[6] += v1 * bf_lo(u1.w); acc[7] += v1 * bf_hi(u1.w);
        acc[0] += v2 * bf_lo(u2.x); acc[1] += v2 * bf_hi(u2.x);
        acc[2] += v2 * bf_lo(u2.y); acc[3] += v2 * bf_hi(u2.y);
        acc[4] += v2 * bf_lo(u2.z); acc[5] += v2 * bf_hi(u2.z);
        acc[6] += v2 * bf_lo(u2.w); acc[7] += v2 * bf_hi(u2.w);
        acc[0] += v3 * bf_lo(u3.x); acc[1] += v3 * bf_hi(u3.x);
        acc[2] += v3 * bf_lo(u3.y); acc[3] += v3 * bf_hi(u3.y);
        acc[4] += v3 * bf_lo(u3.z); acc[5] += v3 * bf_hi(u3.z);
        acc[6] += v3 * bf_lo(u3.w); acc[7] += v3 * bf_hi(u3.w);
    }
    for (; e < end; ++e) {
        int2 d0 = sedge[e];
        uint4 u0 = mapped4[(size_t)d0.x * 16 + q];
        float v0 = __int_as_float(d0.y);
        acc[0] += v0 * bf_lo(u0.x); acc[1] += v0 * bf_hi(u0.x);
        acc[2] += v0 * bf_lo(u0.y); acc[3] += v0 * bf_hi(u0.y);
        acc[4] += v0 * bf_lo(u0.z); acc[5] += v0 * bf_hi(u0.z);
        acc[6] += v0 * bf_lo(u0.w); acc[7] += v0 * bf_hi(u0.w);
    }

    // dual 16-lane reduction: n2 = |a|^2, ab = a.b
    float n2 = 0.f, ab = 0.f;
#pragma unroll
    for (int j = 0; j < 8; ++j) { n2 += acc[j] * acc[j]; ab += acc[j] * bj[j]; }
#pragma unroll
    for (int o = 8; o > 0; o >>= 1) {
        n2 += __shfl_xor(n2, o, 64);
        ab += __shfl_xor(ab, o, 64);
    }

    // exp_map_zero + projection (group-uniform scalars)
    float n = fmaxf(sqrtf(n2), FEPS);
    float t = fast_tanh_clamped(n);
    float s = __fdividef(t, n);
    float en2 = s * s * n2;
    float pn = fmaxf(sqrtf(en2), FEPS);
    float ps = fminf(1.f, __fdividef(1.f - PROJ_EPS, pn));
    float hs = s * ps;
    float x2 = ps * ps * en2;

    // mobius_addition + final projection, |z|^2 analytic
    float xy = hs * ab;
    float cA = 1.f + 2.f * xy + y2;
    float cB = 1.f - x2;
    float den = fmaxf(1.f + 2.f * xy + x2 * y2, FEPS);
    float inv = __fdividef(1.f, den);
    float zn2 = inv * inv * (cA * cA * x2 + 2.f * cA * cB * xy + cB * cB * y2);
    float zn = fmaxf(sqrtf(zn2), FEPS);
    float zs = fminf(1.f, __fdividef(1.f - PROJ_EPS, zn));
    float f = inv * zs;
    float chs = cA * hs * f, cBf = cB * f;

    float4 o0 = make_float4(chs * acc[0] + cBf * bj[0], chs * acc[1] + cBf * bj[1],
                            chs * acc[2] + cBf * bj[2], chs * acc[3] + cBf * bj[3]);
    float4 o1 = make_float4(chs * acc[4] + cBf * bj[4], chs * acc[5] + cBf * bj[5],
                            chs * acc[6] + cBf * bj[6], chs * acc[7] + cBf * bj[7]);
    *reinterpret_cast<float4*>(out + (size_t)row * D + q * 8) = o0;
    *reinterpret_cast<float4*>(out + (size_t)row * D + q * 8 + 4) = o1;
}

extern "C" void kernel_launch(void* const* d_in, const int* in_sizes, int n_in,
                              void* d_out, int out_size, void* d_ws, size_t ws_size,
                              hipStream_t stream) {
    const float* x    = (const float*)d_in[0];
    const float* W    = (const float*)d_in[1];
    const float* bias = (const float*)d_in[2];
    const float* val  = (const float*)d_in[3];
    const int*   rowi = (const int*)d_in[4];
    const int*   coli = (const int*)d_in[5];
    const int N = in_sizes[0] / D;
    const int E = in_sizes[3];

    // ws layout (~32 MB)
    char* ws = (char*)d_ws;
    int*   cnt    = (int*)ws;                         // N*4
    int*   rowptr = (int*)(ws + 400000);              // (N+1)*4
    int*   bsum   = (int*)(ws + 800512);              // 128*4
    int*   bsumx  = (int*)(ws + 801024);              // 128*4
    int*   cursor = (int*)(ws + 801536);              // N*4
    long long* sedge = (long long*)(ws + 1201536);    // E*8
    __hip_bfloat16* mapped = (__hip_bfloat16*)(ws + 1201536 + (size_t)E * 8);  // N*D*2
    float* out = (float*)d_out;

    hipMemsetAsync(cnt, 0, (size_t)N * sizeof(int), stream);
    k_hist<<<(E + 511) / 512, 512, 0, stream>>>(rowi, cnt, E);

    int nb = (N + 1023) / 1024;
    k_scan1<<<nb, 256, 0, stream>>>(cnt, rowptr, bsum, N);
    k_scan2<<<1, 128, 0, stream>>>(bsum, bsumx, nb);
    k_scan3<<<(N + 255) / 256, 256, 0, stream>>>(rowptr, bsumx, cursor, N, E);

    // persistent fused gemm || scatter: 512 blocks = 2/CU (64 KB LDS cap).
    // NT-store scatter needs fewer blocks -> shift toward gemm role.
    const int NT  = (N + 127) / 128;    // 782 gemm tiles
    const int GBg = 416;                // gemm-role blocks (grid-stride tiles)
    const int SBs = 96;                 // scatter-role blocks (grid-stride edges)
    k_gemm_scatter<<<GBg + SBs, 512, 0, stream>>>(x, W, mapped, N, NT, GBg, SBs,
                                                  rowi, coli, val, cursor, sedge, E);

    k_aggfin<<<(N + 15) / 16, 256, 0, stream>>>((const uint4*)mapped,
                                                (const int2*)sedge, rowptr,
                                                bias, out, N);
}

// Round 12
// 128.012 us; speedup vs baseline: 1.0231x; 1.0231x over previous
//
#include <hip/hip_runtime.h>
#include <hip/hip_bf16.h>

#define D 128
#define FEPS 1e-15f
#define PROJ_EPS 1e-5f
#define CPAD 16   // cursor padding: one counter per 64-B line

typedef __attribute__((ext_vector_type(8))) short short8v;
typedef __attribute__((ext_vector_type(4))) float f32x4;

__device__ __forceinline__ unsigned pack_bf16x2(float lo, float hi) {
    __hip_bfloat16 h0 = __float2bfloat16(lo);
    __hip_bfloat16 h1 = __float2bfloat16(hi);
    unsigned u0 = *reinterpret_cast<unsigned short*>(&h0);
    unsigned u1 = *reinterpret_cast<unsigned short*>(&h1);
    return u0 | (u1 << 16);
}

__device__ __forceinline__ float bf_lo(unsigned u) { return __uint_as_float(u << 16); }
__device__ __forceinline__ float bf_hi(unsigned u) { return __uint_as_float(u & 0xffff0000u); }

__device__ __forceinline__ float fast_tanh_clamped(float n) {
    float nc = fminf(n, 15.f);
    float e2 = __expf(2.f * nc);
    return 1.f - __fdividef(2.f, e2 + 1.f);
}

// ---- edge histogram (standalone; runs before scans) ----
__global__ __launch_bounds__(512) void k_hist(const int* __restrict__ rowi,
                                              int* __restrict__ cnt, int E) {
    int e = blockIdx.x * 512 + threadIdx.x;
    if (e < E) atomicAdd(&cnt[rowi[e]], 1);
}

// ---- CSR scan chain (multi-block, proven) ----
__global__ __launch_bounds__(256) void k_scan1(const int* __restrict__ cnt,
                                               int* __restrict__ ex,
                                               int* __restrict__ bsum, int Nn) {
    __shared__ int ts[256];
    int t = threadIdx.x, b = blockIdx.x;
    int base = b * 1024 + t * 4;
    int v0 = (base + 0 < Nn) ? cnt[base + 0] : 0;
    int v1 = (base + 1 < Nn) ? cnt[base + 1] : 0;
    int v2 = (base + 2 < Nn) ? cnt[base + 2] : 0;
    int v3 = (base + 3 < Nn) ? cnt[base + 3] : 0;
    int s = v0 + v1 + v2 + v3;
    ts[t] = s;
    __syncthreads();
    for (int off = 1; off < 256; off <<= 1) {
        int add = (t >= off) ? ts[t - off] : 0;
        __syncthreads();
        ts[t] += add;
        __syncthreads();
    }
    int excl = ts[t] - s;
    if (t == 255) bsum[b] = ts[t];
    if (base + 0 < Nn) ex[base + 0] = excl;
    if (base + 1 < Nn) ex[base + 1] = excl + v0;
    if (base + 2 < Nn) ex[base + 2] = excl + v0 + v1;
    if (base + 3 < Nn) ex[base + 3] = excl + v0 + v1 + v2;
}

__global__ void k_scan2(const int* __restrict__ bsum, int* __restrict__ bsumx, int nb) {
    __shared__ int ts[128];
    int t = threadIdx.x;
    int v = (t < nb) ? bsum[t] : 0;
    ts[t] = v;
    __syncthreads();
    for (int off = 1; off < 128; off <<= 1) {
        int add = (t >= off) ? ts[t - off] : 0;
        __syncthreads();
        ts[t] += add;
        __syncthreads();
    }
    bsumx[t] = ts[t] - v;   // exclusive
}

__global__ __launch_bounds__(256) void k_scan3(int* __restrict__ rowptr,
                                               const int* __restrict__ bsumx,
                                               int* __restrict__ cursorP, int Nn, int E) {
    int i = blockIdx.x * 256 + threadIdx.x;
    if (i < Nn) {
        int v = rowptr[i] + bsumx[i >> 10];
        rowptr[i] = v;
        cursorP[(size_t)i * CPAD] = v;     // padded: 1 counter per 64-B line
    }
    if (i == 0) rowptr[Nn] = E;
}

// ---- fused persistent MFMA GEMM (mapped = logmap(x) @ W) + CSR scatter ----
// blocks [0,GBg): persistent gemm — W staged ONCE, zero-barrier tile loop,
//                 wave-private C staging in separate LDS region.
// blocks [GBg,GBg+SBs): grid-stride CSR scatter, line-padded cursor.
__global__ __launch_bounds__(512) void k_gemm_scatter(
    const float* __restrict__ x, const float* __restrict__ W,
    __hip_bfloat16* __restrict__ mapped, int Nn, int NT, int GBg, int SBs,
    const int* __restrict__ rowi, const int* __restrict__ coli,
    const float* __restrict__ val, int* __restrict__ cursorP,
    int2* __restrict__ sedge, int E)
{
    __shared__ uint4 lsW4[2048];   // 32 KB: W^T, staged once, read-only after
    __shared__ uint4 lsC4[2048];   // 32 KB: C staging, wave-private 4 KB slices

    const int tid = threadIdx.x;

    if (blockIdx.x >= GBg) {
        // ---- scatter role: padded cursor removes line false-sharing ----
        const int stride = SBs * 512;
        int e = (blockIdx.x - GBg) * 512 + tid;
#pragma unroll 2
        for (; e < E; e += stride) {
            int cv = coli[e];
            float vv = val[e];
            int p = atomicAdd(&cursorP[(size_t)rowi[e] * CPAD], 1);
            sedge[p] = make_int2(cv, __float_as_int(vv));
        }
        return;
    }

    const int w = tid >> 6, l = tid & 63;
    const int q = l & 15, khi = l >> 4;

    // ---- stage W^T once, bank-balanced XOR layout ----
#pragma unroll
    for (int it = 0; it < 4; ++it) {
        int i = it * 512 + tid;
        int col = i & 127, kg = i >> 7;
        unsigned p0 = pack_bf16x2(W[(kg * 8 + 0) * D + col], W[(kg * 8 + 1) * D + col]);
        unsigned p1 = pack_bf16x2(W[(kg * 8 + 2) * D + col], W[(kg * 8 + 3) * D + col]);
        unsigned p2 = pack_bf16x2(W[(kg * 8 + 4) * D + col], W[(kg * 8 + 5) * D + col]);
        unsigned p3 = pack_bf16x2(W[(kg * 8 + 6) * D + col], W[(kg * 8 + 7) * D + col]);
        lsW4[col * 16 + (kg ^ (col & 15))] = make_uint4(p0, p1, p2, p3);
    }
    __syncthreads();   // the ONLY barrier — tile loop below is barrier-free

    const short8v* lsB = (const short8v*)lsW4;
    unsigned* lsc = (unsigned*)lsC4;
    const int cbase = w * 1024;            // wave-private 4 KB (1024 words)

#pragma unroll 1
    for (int tt = blockIdx.x; tt < NT; tt += GBg) {
        const int rowbase = tt * 128;
        const int row = rowbase + w * 16 + q;
        const bool rv = row < Nn;
        const float* xr = x + (size_t)row * D;
        float4 xa[8];
        float nn = 0.f;
#pragma unroll
        for (int ks = 0; ks < 4; ++ks) {
            float4 p0 = make_float4(0.f, 0.f, 0.f, 0.f), p1 = p0;
            if (rv) {
                p0 = *reinterpret_cast<const float4*>(xr + ks * 32 + khi * 8);
                p1 = *reinterpret_cast<const float4*>(xr + ks * 32 + khi * 8 + 4);
            }
            xa[2 * ks] = p0; xa[2 * ks + 1] = p1;
            nn += p0.x * p0.x + p0.y * p0.y + p0.z * p0.z + p0.w * p0.w
                + p1.x * p1.x + p1.y * p1.y + p1.z * p1.z + p1.w * p1.w;
        }
        nn += __shfl_xor(nn, 16, 64);
        nn += __shfl_xor(nn, 32, 64);       // full 128-dim row norm^2
        float n = fmaxf(sqrtf(nn), FEPS);
        float c = fminf(n, 1.f - 1e-7f);
        float s = __fdividef(0.5f * __logf(__fdividef(1.f + c, 1.f - c)), n);

        union { unsigned u[4]; short8v v; } af[4];
#pragma unroll
        for (int ks = 0; ks < 4; ++ks) {
            float4 p0 = xa[2 * ks], p1 = xa[2 * ks + 1];
            af[ks].u[0] = pack_bf16x2(s * p0.x, s * p0.y);
            af[ks].u[1] = pack_bf16x2(s * p0.z, s * p0.w);
            af[ks].u[2] = pack_bf16x2(s * p1.x, s * p1.y);
            af[ks].u[3] = pack_bf16x2(s * p1.z, s * p1.w);
        }

        f32x4 acc[8];
#pragma unroll
        for (int t = 0; t < 8; ++t) acc[t] = (f32x4){0.f, 0.f, 0.f, 0.f};

#pragma unroll
        for (int ks = 0; ks < 4; ++ks) {
#pragma unroll
            for (int t = 0; t < 8; ++t) {
                short8v b = lsB[(t * 16 + q) * 16 + ((ks * 4 + khi) ^ q)];
                acc[t] = __builtin_amdgcn_mfma_f32_16x16x32_bf16(af[ks].v, b, acc[t], 0, 0, 0);
            }
        }

        // ---- C staging: wave-private LDS slice, no barriers ----
#pragma unroll
        for (int t = 0; t < 8; ++t) {
#pragma unroll
            for (int r = 0; r < 4; ++r) {
                float self = acc[t][r];
                float other = __shfl_xor(self, 1, 64);
                unsigned pw = (q & 1) ? pack_bf16x2(other, self) : pack_bf16x2(self, other);
                int rl = khi * 4 + r;               // local row 0..15
                int cp = t * 8 + (q >> 1);
                lsc[cbase + rl * 64 + (cp ^ (khi << 3))] = pw;
            }
        }
        // readback own rows, coalesced 16-B/lane global stores
#pragma unroll
        for (int i4 = 0; i4 < 4; ++i4) {
            int rl = i4 * 4 + (l >> 4);             // local row 0..15
            int ro = rowbase + w * 16 + rl;
            int cp4 = (l & 15) * 4;
            uint4 vv = lsC4[(cbase + rl * 64 + (cp4 ^ (i4 << 3))) >> 2];
            if (ro < Nn)
                *reinterpret_cast<uint4*>(mapped + (size_t)ro * D + (l & 15) * 8) = vv;
        }
    }
}

// ---- fused: bias + CSR gather-reduce + expmap + proj + mobius + proj ----
// 16-lane groups: 4 rows/wave, lane l owns dims (l&15)*8..+8 (R8-proven, 44 us)
__global__ __launch_bounds__(256) void k_aggfin(
    const uint4* __restrict__ mapped4, const int2* __restrict__ sedge,
    const int* __restrict__ rowptr, const float* __restrict__ bias,
    float* __restrict__ out, int Nn)
{
    const int tid = threadIdx.x;
    const int w = tid >> 6, l = tid & 63;
    const int g = l >> 4, q = l & 15;
    const int row = blockIdx.x * 16 + w * 4 + g;

    // bias point (identical computation in each 16-lane group)
    float4 rb0 = *reinterpret_cast<const float4*>(bias + q * 8);
    float4 rb1 = *reinterpret_cast<const float4*>(bias + q * 8 + 4);
    float bn2 = rb0.x * rb0.x + rb0.y * rb0.y + rb0.z * rb0.z + rb0.w * rb0.w
              + rb1.x * rb1.x + rb1.y * rb1.y + rb1.z * rb1.z + rb1.w * rb1.w;
#pragma unroll
    for (int o = 8; o > 0; o >>= 1) bn2 += __shfl_xor(bn2, o, 64);
    float bn = fmaxf(sqrtf(bn2), FEPS);
    float bt = fast_tanh_clamped(bn);
    float bs = __fdividef(bt, bn);
    float ben2 = bs * bs * bn2;
    float bpn = fmaxf(sqrtf(ben2), FEPS);
    float bps = fminf(1.f, __fdividef(1.f - PROJ_EPS, bpn));
    float bsc = bs * bps;
    float y2 = bps * bps * ben2;
    float bj[8] = { rb0.x * bsc, rb0.y * bsc, rb0.z * bsc, rb0.w * bsc,
                    rb1.x * bsc, rb1.y * bsc, rb1.z * bsc, rb1.w * bsc };

    if (row >= Nn) return;
    int beg = rowptr[row], end = rowptr[row + 1];

    float acc[8] = {0.f, 0.f, 0.f, 0.f, 0.f, 0.f, 0.f, 0.f};
    int e = beg;
    for (; e + 3 < end; e += 4) {         // 4 gathers in flight
        int2 d0 = sedge[e], d1 = sedge[e + 1], d2 = sedge[e + 2], d3 = sedge[e + 3];
        uint4 u0 = mapped4[(size_t)d0.x * 16 + q];
        uint4 u1 = mapped4[(size_t)d1.x * 16 + q];
        uint4 u2 = mapped4[(size_t)d2.x * 16 + q];
        uint4 u3 = mapped4[(size_t)d3.x * 16 + q];
        float v0 = __int_as_float(d0.y), v1 = __int_as_float(d1.y);
        float v2 = __int_as_float(d2.y), v3 = __int_as_float(d3.y);
        acc[0] += v0 * bf_lo(u0.x); acc[1] += v0 * bf_hi(u0.x);
        acc[2] += v0 * bf_lo(u0.y); acc[3] += v0 * bf_hi(u0.y);
        acc[4] += v0 * bf_lo(u0.z); acc[5] += v0 * bf_hi(u0.z);
        acc[6] += v0 * bf_lo(u0.w); acc[7] += v0 * bf_hi(u0.w);
        acc[0] += v1 * bf_lo(u1.x); acc[1] += v1 * bf_hi(u1.x);
        acc[2] += v1 * bf_lo(u1.y); acc[3] += v1 * bf_hi(u1.y);
        acc[4] += v1 * bf_lo(u1.z); acc[5] += v1 * bf_hi(u1.z);
        acc[6] += v1 * bf_lo(u1.w); acc[7] += v1 * bf_hi(u1.w);
        acc[0] += v2 * bf_lo(u2.x); acc[1] += v2 * bf_hi(u2.x);
        acc[2] += v2 * bf_lo(u2.y); acc[3] += v2 * bf_hi(u2.y);
        acc[4] += v2 * bf_lo(u2.z); acc[5] += v2 * bf_hi(u2.z);
        acc[6] += v2 * bf_lo(u2.w); acc[7] += v2 * bf_hi(u2.w);
        acc[0] += v3 * bf_lo(u3.x); acc[1] += v3 * bf_hi(u3.x);
        acc[2] += v3 * bf_lo(u3.y); acc[3] += v3 * bf_hi(u3.y);
        acc[4] += v3 * bf_lo(u3.z); acc[5] += v3 * bf_hi(u3.z);
        acc[6] += v3 * bf_lo(u3.w); acc[7] += v3 * bf_hi(u3.w);
    }
    for (; e < end; ++e) {
        int2 d0 = sedge[e];
        uint4 u0 = mapped4[(size_t)d0.x * 16 + q];
        float v0 = __int_as_float(d0.y);
        acc[0] += v0 * bf_lo(u0.x); acc[1] += v0 * bf_hi(u0.x);
        acc[2] += v0 * bf_lo(u0.y); acc[3] += v0 * bf_hi(u0.y);
        acc[4] += v0 * bf_lo(u0.z); acc[5] += v0 * bf_hi(u0.z);
        acc[6] += v0 * bf_lo(u0.w); acc[7] += v0 * bf_hi(u0.w);
    }

    // dual 16-lane reduction: n2 = |a|^2, ab = a.b
    float n2 = 0.f, ab = 0.f;
#pragma unroll
    for (int j = 0; j < 8; ++j) { n2 += acc[j] * acc[j]; ab += acc[j] * bj[j]; }
#pragma unroll
    for (int o = 8; o > 0; o >>= 1) {
        n2 += __shfl_xor(n2, o, 64);
        ab += __shfl_xor(ab, o, 64);
    }

    // exp_map_zero + projection (group-uniform scalars)
    float n = fmaxf(sqrtf(n2), FEPS);
    float t = fast_tanh_clamped(n);
    float s = __fdividef(t, n);
    float en2 = s * s * n2;
    float pn = fmaxf(sqrtf(en2), FEPS);
    float ps = fminf(1.f, __fdividef(1.f - PROJ_EPS, pn));
    float hs = s * ps;
    float x2 = ps * ps * en2;

    // mobius_addition + final projection, |z|^2 analytic
    float xy = hs * ab;
    float cA = 1.f + 2.f * xy + y2;
    float cB = 1.f - x2;
    float den = fmaxf(1.f + 2.f * xy + x2 * y2, FEPS);
    float inv = __fdividef(1.f, den);
    float zn2 = inv * inv * (cA * cA * x2 + 2.f * cA * cB * xy + cB * cB * y2);
    float zn = fmaxf(sqrtf(zn2), FEPS);
    float zs = fminf(1.f, __fdividef(1.f - PROJ_EPS, zn));
    float f = inv * zs;
    float chs = cA * hs * f, cBf = cB * f;

    float4 o0 = make_float4(chs * acc[0] + cBf * bj[0], chs * acc[1] + cBf * bj[1],
                            chs * acc[2] + cBf * bj[2], chs * acc[3] + cBf * bj[3]);
    float4 o1 = make_float4(chs * acc[4] + cBf * bj[4], chs * acc[5] + cBf * bj[5],
                            chs * acc[6] + cBf * bj[6], chs * acc[7] + cBf * bj[7]);
    *reinterpret_cast<float4*>(out + (size_t)row * D + q * 8) = o0;
    *reinterpret_cast<float4*>(out + (size_t)row * D + q * 8 + 4) = o1;
}

extern "C" void kernel_launch(void* const* d_in, const int* in_sizes, int n_in,
                              void* d_out, int out_size, void* d_ws, size_t ws_size,
                              hipStream_t stream) {
    const float* x    = (const float*)d_in[0];
    const float* W    = (const float*)d_in[1];
    const float* bias = (const float*)d_in[2];
    const float* val  = (const float*)d_in[3];
    const int*   rowi = (const int*)d_in[4];
    const int*   coli = (const int*)d_in[5];
    const int N = in_sizes[0] / D;
    const int E = in_sizes[3];

    // ws layout (~38 MB; proven ws >= 51.2 MB in round 3)
    char* ws = (char*)d_ws;
    int*   cnt     = (int*)ws;                        // N*4
    int*   rowptr  = (int*)(ws + 400000);             // (N+1)*4
    int*   bsum    = (int*)(ws + 800512);             // 128*4
    int*   bsumx   = (int*)(ws + 801024);             // 128*4
    int*   cursorP = (int*)(ws + 801536);             // N*16*4 = 6.4 MB (line-padded)
    int2*  sedge   = (int2*)(ws + 801536 + 6400000);  // E*8
    __hip_bfloat16* mapped =
        (__hip_bfloat16*)(ws + 801536 + 6400000 + (size_t)E * 8);  // N*D*2
    float* out = (float*)d_out;

    hipMemsetAsync(cnt, 0, (size_t)N * sizeof(int), stream);
    k_hist<<<(E + 511) / 512, 512, 0, stream>>>(rowi, cnt, E);

    int nb = (N + 1023) / 1024;
    k_scan1<<<nb, 256, 0, stream>>>(cnt, rowptr, bsum, N);
    k_scan2<<<1, 128, 0, stream>>>(bsum, bsumx, nb);
    k_scan3<<<(N + 255) / 256, 256, 0, stream>>>(rowptr, bsumx, cursorP, N, E);

    // persistent fused gemm || scatter: 512 blocks = 2/CU (64 KB LDS cap).
    const int NT  = (N + 127) / 128;    // 782 gemm tiles
    const int GBg = 384;                // gemm-role blocks (grid-stride tiles)
    const int SBs = 128;                // scatter-role blocks (grid-stride edges)
    k_gemm_scatter<<<GBg + SBs, 512, 0, stream>>>(x, W, mapped, N, NT, GBg, SBs,
                                                  rowi, coli, val, cursorP, sedge, E);

    k_aggfin<<<(N + 15) / 16, 256, 0, stream>>>((const uint4*)mapped,
                                                (const int2*)sedge, rowptr,
                                                bias, out, N);
}